// Round 3
// baseline (2311.151 us; speedup 1.0000x reference)
//
#include <hip/hip_runtime.h>

#define B_   4
#define NB_  262144
#define NA_  8192

// ---------------- helpers ----------------
__device__ __forceinline__ float bflo(unsigned int u){ return __uint_as_float(u << 16); }
__device__ __forceinline__ float bfhi(unsigned int u){ return __uint_as_float(u & 0xffff0000u); }
__device__ __forceinline__ unsigned short f2bf(float f){
  unsigned int u = __float_as_uint(f);
  u += 0x7fffu + ((u >> 16) & 1u);   // round-to-nearest-even
  return (unsigned short)(u >> 16);
}
__device__ __forceinline__ float softplus_f(float v){
  // matches jax.nn.softplus = max(v,0) + log1p(exp(-|v|))
  return fmaxf(v, 0.0f) + __logf(1.0f + __expf(-fabsf(v)));
}

__device__ __forceinline__ void store32f(float* dst, const float* v){
  float4* p = reinterpret_cast<float4*>(dst);
  #pragma unroll
  for (int q = 0; q < 8; ++q)
    p[q] = make_float4(v[4*q+0], v[4*q+1], v[4*q+2], v[4*q+3]);
}

// stage 32 f32 elements from src into 16 packed-bf16-pair LDS rows r0..r0+15
// row r holds elements 2(r-r0), 2(r-r0)+1 of this 32-chunk
__device__ __forceinline__ void stage32(unsigned int* xbuf, int tid, int r0,
                                        const float* __restrict__ src){
  const float4* p = reinterpret_cast<const float4*>(src);
  #pragma unroll
  for (int q = 0; q < 8; ++q){
    float4 v = p[q];
    xbuf[(r0 + 2*q    )*256 + tid] = (unsigned int)f2bf(v.x) | ((unsigned int)f2bf(v.y) << 16);
    xbuf[(r0 + 2*q + 1)*256 + tid] = (unsigned int)f2bf(v.z) | ((unsigned int)f2bf(v.w) << 16);
  }
}

// Shared MLP tail: layers 2 (64->64) and 3 (64->32); h1 in hbuf rows [k][tid] (f32).
// hbuf columns are thread-private -> no barriers.
__device__ __forceinline__ void mlp_tail(float* hbuf, int tid,
                                         const float* __restrict__ W2, const float* __restrict__ B2,
                                         const float* __restrict__ W3, const float* __restrict__ B3,
                                         float* out)
{
  float acc[64];
  #pragma unroll
  for (int j = 0; j < 64; ++j) acc[j] = B2[j];
  for (int k = 0; k < 64; ++k){
    float hk = hbuf[k*256 + tid];
    const float* w = W2 + k*64;          // wave-uniform address -> scalar loads
    #pragma unroll
    for (int j = 0; j < 64; ++j) acc[j] = fmaf(hk, w[j], acc[j]);
  }
  #pragma unroll
  for (int j = 0; j < 64; ++j) hbuf[j*256 + tid] = softplus_f(acc[j]);

  float a3[32];
  #pragma unroll
  for (int j = 0; j < 32; ++j) a3[j] = B3[j];
  for (int k = 0; k < 64; ++k){
    float hk = hbuf[k*256 + tid];
    const float* w = W3 + k*32;
    #pragma unroll
    for (int j = 0; j < 32; ++j) a3[j] = fmaf(hk, w[j], a3[j]);
  }
  #pragma unroll
  for (int j = 0; j < 32; ++j) out[j] = softplus_f(a3[j]);
}

// ---------------- weight prep: concat the 18 f32 arrays into one W buffer ----------------
struct WPtrs { const float* p[18]; };

__global__ __launch_bounds__(256) void prep_kernel(WPtrs wp, float* __restrict__ W){
  int i = blockIdx.x * 256 + threadIdx.x;
  if (i >= 39392) return;
  int idx = i;
  const int sizes[18] = {8192,64,4096,64,2048,32,
                         6144,64,4096,64,2048,32,
                         6144,64,4096,64,2048,32};
  #pragma unroll
  for (int s = 0; s < 18; ++s){
    if (idx < sizes[s]){
      W[i] = wp.p[s][idx];
      return;
    }
    idx -= sizes[s];
  }
}

// ---------------- stage 1: bonds MLP (128->64->64->32) + scatter ----------------
// W layout (e): w1[128][64] @0 | b1 @8192 | w2 @8256 | b2 @12352 | w3 @12416 | b3 @14464
__global__ __launch_bounds__(256) void bonds_kernel(
    const float* __restrict__ bonds,
    const int* __restrict__ ba1,
    const int* __restrict__ ba2,
    const float* __restrict__ atoms,
    const float* __restrict__ state,
    const float* __restrict__ W,
    float* __restrict__ bonds_out,
    float* __restrict__ bta,
    float* __restrict__ counts)
{
  __shared__ unsigned int xbuf[64*256];   // 64 KB: x as packed bf16 pairs, reused as f32 h
  float* hbuf = (float*)xbuf;
  const int tid = threadIdx.x;
  const int b = blockIdx.y;
  const size_t bondIdx = (size_t)b*NB_ + (size_t)blockIdx.x*256 + tid;
  const int i1 = ba1[bondIdx];
  const int i2 = ba2[bondIdx];

  stage32(xbuf, tid, 0,  atoms + ((size_t)b*NA_ + i1)*32);
  stage32(xbuf, tid, 16, atoms + ((size_t)b*NA_ + i2)*32);
  stage32(xbuf, tid, 32, bonds + bondIdx*32);
  stage32(xbuf, tid, 48, state + (size_t)b*32);

  // layer 1: 128 -> 64.  k-outer, j fully unrolled into 64 reg accumulators.
  {
    float acc[64];
    const float* Bl = W + 8192;
    #pragma unroll
    for (int j = 0; j < 64; ++j) acc[j] = Bl[j];
    for (int k2 = 0; k2 < 64; ++k2){
      unsigned int px = xbuf[k2*256 + tid];
      float x0 = bflo(px), x1 = bfhi(px);
      const float* w = W + k2*128;       // w1 rows 2*k2, 2*k2+1; wave-uniform
      #pragma unroll
      for (int j = 0; j < 64; ++j) acc[j] = fmaf(x0, w[j], acc[j]);
      #pragma unroll
      for (int j = 0; j < 64; ++j) acc[j] = fmaf(x1, w[64+j], acc[j]);
    }
    #pragma unroll
    for (int j = 0; j < 64; ++j) hbuf[j*256 + tid] = softplus_f(acc[j]);
  }

  float out[32];
  mlp_tail(hbuf, tid, W + 8256, W + 12352, W + 12416, W + 14464, out);

  store32f(bonds_out + bondIdx*32, out);

  float* bt = bta + ((size_t)b*NA_ + i1)*32;
  #pragma unroll
  for (int f = 0; f < 32; ++f) unsafeAtomicAdd(bt + f, out[f]);
  unsafeAtomicAdd(counts + (size_t)b*NA_ + i1, 1.0f);
}

// ---------------- stage 2: atoms MLP (96->64->64->32) + global mean partials ----------------
// W layout (v, local): w1[96][64] @0 | b1 @6144 | w2 @6208 | b2 @10304 | w3 @10368 | b3 @12416
__global__ __launch_bounds__(256) void atoms_kernel(
    const float* __restrict__ atoms,
    const float* __restrict__ state,
    const float* __restrict__ W,
    const float* __restrict__ bta,
    const float* __restrict__ counts,
    float* __restrict__ atoms_out,
    float* __restrict__ bondsum,
    float* __restrict__ atomsum)
{
  __shared__ unsigned int xbuf[64*256];
  float* xf = (float*)xbuf;
  const int tid = threadIdx.x;
  const int lane = tid & 63;
  const int b = blockIdx.y;
  const size_t rowIdx = (size_t)b*NA_ + (size_t)blockIdx.x*256 + tid;

  float braw[32];
  {
    const float4* pb = reinterpret_cast<const float4*>(bta + rowIdx*32);
    #pragma unroll
    for (int q = 0; q < 8; ++q){
      float4 v = pb[q];
      braw[q*4+0]=v.x; braw[q*4+1]=v.y; braw[q*4+2]=v.z; braw[q*4+3]=v.w;
    }
  }
  const float inv = 1.0f / counts[rowIdx];
  #pragma unroll
  for (int f = 0; f < 32; ++f) xf[f*256 + tid] = braw[f] * inv;   // f32 rows 0..31
  stage32(xbuf, tid, 32, atoms + rowIdx*32);        // v_in elems 32..63 (packed rows 32..47)
  stage32(xbuf, tid, 48, state + (size_t)b*32);     // v_in elems 64..95 (packed rows 48..63)

  // layer 1: k = 0..31 from f32 rows; k = 32..95 from packed rows
  {
    float acc[64];
    const float* Bl = W + 6144;
    #pragma unroll
    for (int j = 0; j < 64; ++j) acc[j] = Bl[j];
    for (int k = 0; k < 32; ++k){
      float xv = xf[k*256 + tid];
      const float* w = W + k*64;
      #pragma unroll
      for (int j = 0; j < 64; ++j) acc[j] = fmaf(xv, w[j], acc[j]);
    }
    for (int k2 = 0; k2 < 32; ++k2){
      unsigned int px = xbuf[(32 + k2)*256 + tid];
      float x0 = bflo(px), x1 = bfhi(px);
      const float* w = W + (32 + k2*2)*64;
      #pragma unroll
      for (int j = 0; j < 64; ++j) acc[j] = fmaf(x0, w[j], acc[j]);
      #pragma unroll
      for (int j = 0; j < 64; ++j) acc[j] = fmaf(x1, w[64+j], acc[j]);
    }
    #pragma unroll
    for (int j = 0; j < 64; ++j) xf[j*256 + tid] = softplus_f(acc[j]);
  }

  float out[32];
  mlp_tail(xf, tid, W + 6208, W + 10304, W + 10368, W + 12416, out);
  store32f(atoms_out + rowIdx*32, out);

  // per-wave reductions: sum over atoms of braw == sum over bonds of bonds_out
  #pragma unroll
  for (int f = 0; f < 32; ++f){
    float v = braw[f];
    #pragma unroll
    for (int s = 1; s < 64; s <<= 1) v += __shfl_xor(v, s);
    if (lane == 0) unsafeAtomicAdd(&bondsum[b*32 + f], v);
  }
  #pragma unroll
  for (int f = 0; f < 32; ++f){
    float v = out[f];
    #pragma unroll
    for (int s = 1; s < 64; s <<= 1) v += __shfl_xor(v, s);
    if (lane == 0) unsafeAtomicAdd(&atomsum[b*32 + f], v);
  }
}

// ---------------- stage 3: state MLP (96->64->64->32), 4 rows ----------------
__global__ __launch_bounds__(256) void state_kernel(
    const float* __restrict__ state,
    const float* __restrict__ W,
    const float* __restrict__ bondsum,
    const float* __restrict__ atomsum,
    float* __restrict__ state_out)
{
  __shared__ float uin[4][96];
  __shared__ float h1s[4][64];
  __shared__ float h2s[4][64];
  const int tid = threadIdx.x;
  const int b = tid >> 6;
  const int j = tid & 63;
  if (j < 32){
    uin[b][j]      = bondsum[b*32 + j] * (1.0f/(float)NB_);
    uin[b][32 + j] = atomsum[b*32 + j] * (1.0f/(float)NA_);
    uin[b][64 + j] = state[(size_t)b*32 + j];
  }
  __syncthreads();
  float a1 = W[6144 + j];
  for (int k = 0; k < 96; ++k) a1 = fmaf(uin[b][k], W[k*64 + j], a1);
  h1s[b][j] = softplus_f(a1);
  __syncthreads();
  float a2 = W[10304 + j];
  for (int k = 0; k < 64; ++k) a2 = fmaf(h1s[b][k], W[6208 + k*64 + j], a2);
  h2s[b][j] = softplus_f(a2);
  __syncthreads();
  if (j < 32){
    float a3 = W[12416 + j];
    for (int k = 0; k < 64; ++k) a3 = fmaf(h2s[b][k], W[10368 + k*32 + j], a3);
    state_out[b*32 + j] = softplus_f(a3);
  }
}

// ---------------- launcher ----------------
// ws floats: bta[1048576] | counts[32768] | bondsum[128] | atomsum[128] | W[39392]
extern "C" void kernel_launch(void* const* d_in, const int* in_sizes, int n_in,
                              void* d_out, int out_size, void* d_ws, size_t ws_size,
                              hipStream_t stream)
{
  (void)in_sizes; (void)n_in; (void)out_size; (void)ws_size;
  const float* bonds = (const float*)d_in[0];
  const int*   ba1   = (const int*)d_in[1];
  const int*   ba2   = (const int*)d_in[2];
  const float* atoms = (const float*)d_in[3];
  const float* state = (const float*)d_in[4];

  float* ws      = (float*)d_ws;
  float* bta     = ws;
  float* counts  = ws + 1048576;
  float* bondsum = ws + 1081344;
  float* atomsum = ws + 1081472;
  float* W       = ws + 1081600;

  hipMemsetAsync(d_ws, 0, 1081600 * sizeof(float), stream);

  WPtrs wp;
  for (int s = 0; s < 18; ++s) wp.p[s] = (const float*)d_in[5 + s];
  prep_kernel<<<154, 256, 0, stream>>>(wp, W);

  float* out_bonds = (float*)d_out;
  float* out_atoms = out_bonds + (size_t)B_*NB_*32;
  float* out_state = out_atoms + (size_t)B_*NA_*32;

  bonds_kernel<<<dim3(NB_/256, B_), 256, 0, stream>>>(bonds, ba1, ba2, atoms, state,
                                                      W, out_bonds, bta, counts);
  atoms_kernel<<<dim3(NA_/256, B_), 256, 0, stream>>>(atoms, state, W + 14496,
                                                      bta, counts, out_atoms, bondsum, atomsum);
  state_kernel<<<1, 256, 0, stream>>>(state, W + 26944, bondsum, atomsum, out_state);
}

// Round 4
// 904.016 us; speedup vs baseline: 2.5565x; 2.5565x over previous
//
#include <hip/hip_runtime.h>

#define B_   4
#define NB_  262144
#define NA_  8192
#define NB_SHIFT 18

// ---------------- helpers ----------------
__device__ __forceinline__ float bflo(unsigned int u){ return __uint_as_float(u << 16); }
__device__ __forceinline__ float bfhi(unsigned int u){ return __uint_as_float(u & 0xffff0000u); }
__device__ __forceinline__ unsigned short f2bf(float f){
  unsigned int u = __float_as_uint(f);
  u += 0x7fffu + ((u >> 16) & 1u);   // round-to-nearest-even
  return (unsigned short)(u >> 16);
}
__device__ __forceinline__ unsigned int packbf(float a, float b){
  return (unsigned int)f2bf(a) | ((unsigned int)f2bf(b) << 16);
}
__device__ __forceinline__ float softplus_f(float v){
  return fmaxf(v, 0.0f) + __logf(1.0f + __expf(-fabsf(v)));
}
__device__ __forceinline__ void store32f(float* dst, const float* v){
  float4* p = reinterpret_cast<float4*>(dst);
  #pragma unroll
  for (int q = 0; q < 8; ++q)
    p[q] = make_float4(v[4*q+0], v[4*q+1], v[4*q+2], v[4*q+3]);
}

// stage 32 f32 from src into 16 packed-bf16-pair LDS rows r0..r0+15 (row stride = ncol)
__device__ __forceinline__ void stage32(unsigned int* xbuf, int tid, int r0,
                                        const float* __restrict__ src, int ncol){
  const float4* p = reinterpret_cast<const float4*>(src);
  #pragma unroll
  for (int q = 0; q < 8; ++q){
    float4 v = p[q];
    xbuf[(r0 + 2*q    )*ncol + tid] = packbf(v.x, v.y);
    xbuf[(r0 + 2*q + 1)*ncol + tid] = packbf(v.z, v.w);
  }
}

// layers 2 (64->64) + 3 (64->32); h1 in 32 packed rows of hbuf. Columns thread-private.
__device__ __forceinline__ void mlp_tail_packed(unsigned int* hbuf, int tid, int ncol,
                                         const float* __restrict__ W2, const float* __restrict__ B2,
                                         const float* __restrict__ W3, const float* __restrict__ B3,
                                         float* out)
{
  float acc[64];
  #pragma unroll
  for (int j = 0; j < 64; ++j) acc[j] = B2[j];
  for (int k2 = 0; k2 < 32; ++k2){
    unsigned int px = hbuf[k2*ncol + tid];
    float x0 = bflo(px), x1 = bfhi(px);
    const float* w = W2 + k2*128;        // W2 rows 2k2, 2k2+1 (64 wide each)
    #pragma unroll
    for (int j = 0; j < 64; ++j) acc[j] = fmaf(x0, w[j], acc[j]);
    #pragma unroll
    for (int j = 0; j < 64; ++j) acc[j] = fmaf(x1, w[64+j], acc[j]);
  }
  #pragma unroll
  for (int j2 = 0; j2 < 32; ++j2)
    hbuf[j2*ncol + tid] = packbf(softplus_f(acc[2*j2]), softplus_f(acc[2*j2+1]));

  float a3[32];
  #pragma unroll
  for (int j = 0; j < 32; ++j) a3[j] = B3[j];
  for (int k2 = 0; k2 < 32; ++k2){
    unsigned int px = hbuf[k2*ncol + tid];
    float x0 = bflo(px), x1 = bfhi(px);
    const float* w = W3 + k2*64;         // W3 rows 2k2, 2k2+1 (32 wide each)
    #pragma unroll
    for (int j = 0; j < 32; ++j) a3[j] = fmaf(x0, w[j], a3[j]);
    #pragma unroll
    for (int j = 0; j < 32; ++j) a3[j] = fmaf(x1, w[32+j], a3[j]);
  }
  #pragma unroll
  for (int j = 0; j < 32; ++j) out[j] = softplus_f(a3[j]);
}

// ---------------- weight prep: concat the 18 f32 arrays ----------------
struct WPtrs { const float* p[18]; };

__global__ __launch_bounds__(256) void prep_kernel(WPtrs wp, float* __restrict__ W){
  int i = blockIdx.x * 256 + threadIdx.x;
  if (i >= 39392) return;
  int idx = i;
  const int sizes[18] = {8192,64,4096,64,2048,32,
                         6144,64,4096,64,2048,32,
                         6144,64,4096,64,2048,32};
  #pragma unroll
  for (int s = 0; s < 18; ++s){
    if (idx < sizes[s]){ W[i] = wp.p[s][idx]; return; }
    idx -= sizes[s];
  }
}

// ---------------- CSR build ----------------
__global__ __launch_bounds__(256) void hist_kernel(const int* __restrict__ ba1,
                                                   int* __restrict__ counts){
  int i = blockIdx.x * 256 + threadIdx.x;      // [0, B*NB)
  int b = i >> NB_SHIFT;
  atomicAdd(&counts[b*NA_ + ba1[i]], 1);
}

__global__ __launch_bounds__(1024) void scan_kernel(const int* __restrict__ counts,
                                                    int* __restrict__ offsets,
                                                    int* __restrict__ woff){
  __shared__ int s[1024];
  const int tid = threadIdx.x;
  const int base = tid * 32;
  int local[32]; int sum = 0;
  #pragma unroll
  for (int i = 0; i < 32; ++i){ local[i] = counts[base + i]; sum += local[i]; }
  s[tid] = sum;
  __syncthreads();
  for (int off = 1; off < 1024; off <<= 1){
    int v = (tid >= off) ? s[tid - off] : 0;
    __syncthreads();
    s[tid] += v;
    __syncthreads();
  }
  int run = s[tid] - sum;                       // exclusive base for this chunk
  #pragma unroll
  for (int i = 0; i < 32; ++i){
    offsets[base + i] = run; woff[base + i] = run; run += local[i];
  }
}

__global__ __launch_bounds__(256) void fill_kernel(const int* __restrict__ ba1,
                                                   int* __restrict__ woff,
                                                   int* __restrict__ list){
  int i = blockIdx.x * 256 + threadIdx.x;
  int b = i >> NB_SHIFT;
  int pos = atomicAdd(&woff[b*NA_ + ba1[i]], 1);
  list[pos] = i & (NB_ - 1);                    // bond index within batch
}

// ---------------- stage 1: bonds MLP (128->64->64->32), no scatter ----------------
// W(e): w1[128][64] @0 | b1 @8192 | w2 @8256 | b2 @12352 | w3 @12416 | b3 @14464
__global__ __launch_bounds__(256) void bonds_kernel(
    const float* __restrict__ bonds,
    const int* __restrict__ ba1,
    const int* __restrict__ ba2,
    const float* __restrict__ atoms,
    const float* __restrict__ state,
    const float* __restrict__ W,
    float* __restrict__ bonds_out)
{
  __shared__ unsigned int xbuf[32*256];   // 32 KB
  const int tid = threadIdx.x;
  const int b = blockIdx.y;
  const size_t bondIdx = (size_t)b*NB_ + (size_t)blockIdx.x*256 + tid;
  const int i1 = ba1[bondIdx];
  const int i2 = ba2[bondIdx];

  float acc[64];
  {
    const float* Bl = W + 8192;
    #pragma unroll
    for (int j = 0; j < 64; ++j) acc[j] = Bl[j];
  }
  // phase A: x elems 0..63 (a1, a2)
  stage32(xbuf, tid, 0,  atoms + ((size_t)b*NA_ + i1)*32, 256);
  stage32(xbuf, tid, 16, atoms + ((size_t)b*NA_ + i2)*32, 256);
  for (int k2 = 0; k2 < 32; ++k2){
    unsigned int px = xbuf[k2*256 + tid];
    float x0 = bflo(px), x1 = bfhi(px);
    const float* w = W + k2*128;               // w1 rows 2k2, 2k2+1
    #pragma unroll
    for (int j = 0; j < 64; ++j) acc[j] = fmaf(x0, w[j], acc[j]);
    #pragma unroll
    for (int j = 0; j < 64; ++j) acc[j] = fmaf(x1, w[64+j], acc[j]);
  }
  // phase B: x elems 64..127 (bond, state) — overwrite rows 0..31 (thread-private, safe)
  stage32(xbuf, tid, 0,  bonds + bondIdx*32,   256);
  stage32(xbuf, tid, 16, state + (size_t)b*32, 256);
  for (int k2 = 0; k2 < 32; ++k2){
    unsigned int px = xbuf[k2*256 + tid];
    float x0 = bflo(px), x1 = bfhi(px);
    const float* w = W + 4096 + k2*128;        // w1 rows 64+2k2, 65+2k2
    #pragma unroll
    for (int j = 0; j < 64; ++j) acc[j] = fmaf(x0, w[j], acc[j]);
    #pragma unroll
    for (int j = 0; j < 64; ++j) acc[j] = fmaf(x1, w[64+j], acc[j]);
  }
  #pragma unroll
  for (int j2 = 0; j2 < 32; ++j2)
    xbuf[j2*256 + tid] = packbf(softplus_f(acc[2*j2]), softplus_f(acc[2*j2+1]));

  float out[32];
  mlp_tail_packed(xbuf, tid, 256, W + 8256, W + 12352, W + 12416, W + 14464, out);
  store32f(bonds_out + bondIdx*32, out);
}

// ---------------- stage 2: gather + atoms MLP (96->64->64->32) ----------------
// W(v): w1[96][64] @0 | b1 @6144 | w2 @6208 | b2 @10304 | w3 @10368 | b3 @12416
__global__ __launch_bounds__(64) void atoms_kernel(
    const float* __restrict__ atoms,
    const float* __restrict__ state,
    const float* __restrict__ W,
    const int* __restrict__ counts,
    const int* __restrict__ offsets,
    const int* __restrict__ list,
    const float* __restrict__ bonds_out,
    float* __restrict__ atoms_out,
    float* __restrict__ bondsum,
    float* __restrict__ atomsum)
{
  __shared__ unsigned int xbuf[48*64];   // 12 KB
  const int tid = threadIdx.x;           // one wave
  const int b = blockIdx.y;
  const int row = b*NA_ + blockIdx.x*64 + tid;

  const int c = counts[row];
  const int o = offsets[row];
  float braw[32];
  #pragma unroll
  for (int f = 0; f < 32; ++f) braw[f] = 0.0f;
  for (int t = 0; t < c; ++t){
    int idx = list[o + t];
    const float4* pr = reinterpret_cast<const float4*>(bonds_out + ((size_t)b*NB_ + idx)*32);
    #pragma unroll
    for (int q = 0; q < 8; ++q){
      float4 v = pr[q];
      braw[4*q+0] += v.x; braw[4*q+1] += v.y; braw[4*q+2] += v.z; braw[4*q+3] += v.w;
    }
  }
  const float inv = 1.0f / (float)c;
  #pragma unroll
  for (int q = 0; q < 16; ++q)
    xbuf[q*64 + tid] = packbf(braw[2*q]*inv, braw[2*q+1]*inv);     // v_in 0..31
  stage32(xbuf, tid, 16, atoms + (size_t)row*32,  64);             // v_in 32..63
  stage32(xbuf, tid, 32, state + (size_t)b*32,    64);             // v_in 64..95

  // layer 1: 48 packed rows
  float acc[64];
  {
    const float* Bl = W + 6144;
    #pragma unroll
    for (int j = 0; j < 64; ++j) acc[j] = Bl[j];
  }
  for (int k2 = 0; k2 < 48; ++k2){
    unsigned int px = xbuf[k2*64 + tid];
    float x0 = bflo(px), x1 = bfhi(px);
    const float* w = W + k2*128;               // w1 rows 2k2, 2k2+1
    #pragma unroll
    for (int j = 0; j < 64; ++j) acc[j] = fmaf(x0, w[j], acc[j]);
    #pragma unroll
    for (int j = 0; j < 64; ++j) acc[j] = fmaf(x1, w[64+j], acc[j]);
  }
  #pragma unroll
  for (int j2 = 0; j2 < 32; ++j2)
    xbuf[j2*64 + tid] = packbf(softplus_f(acc[2*j2]), softplus_f(acc[2*j2+1]));

  float out[32];
  mlp_tail_packed(xbuf, tid, 64, W + 6208, W + 10304, W + 10368, W + 12416, out);
  store32f(atoms_out + (size_t)row*32, out);

  // block = one wave: shuffle-reduce then one atomic per feature
  #pragma unroll
  for (int f = 0; f < 32; ++f){
    float v = braw[f];
    #pragma unroll
    for (int s = 1; s < 64; s <<= 1) v += __shfl_xor(v, s);
    if (tid == 0) unsafeAtomicAdd(&bondsum[b*32 + f], v);
  }
  #pragma unroll
  for (int f = 0; f < 32; ++f){
    float v = out[f];
    #pragma unroll
    for (int s = 1; s < 64; s <<= 1) v += __shfl_xor(v, s);
    if (tid == 0) unsafeAtomicAdd(&atomsum[b*32 + f], v);
  }
}

// ---------------- stage 3: state MLP (96->64->64->32), 4 rows ----------------
__global__ __launch_bounds__(256) void state_kernel(
    const float* __restrict__ state,
    const float* __restrict__ W,
    const float* __restrict__ bondsum,
    const float* __restrict__ atomsum,
    float* __restrict__ state_out)
{
  __shared__ float uin[4][96];
  __shared__ float h1s[4][64];
  __shared__ float h2s[4][64];
  const int tid = threadIdx.x;
  const int b = tid >> 6;
  const int j = tid & 63;
  if (j < 32){
    uin[b][j]      = bondsum[b*32 + j] * (1.0f/(float)NB_);
    uin[b][32 + j] = atomsum[b*32 + j] * (1.0f/(float)NA_);
    uin[b][64 + j] = state[(size_t)b*32 + j];
  }
  __syncthreads();
  float a1 = W[6144 + j];
  for (int k = 0; k < 96; ++k) a1 = fmaf(uin[b][k], W[k*64 + j], a1);
  h1s[b][j] = softplus_f(a1);
  __syncthreads();
  float a2 = W[10304 + j];
  for (int k = 0; k < 64; ++k) a2 = fmaf(h1s[b][k], W[6208 + k*64 + j], a2);
  h2s[b][j] = softplus_f(a2);
  __syncthreads();
  if (j < 32){
    float a3 = W[12416 + j];
    for (int k = 0; k < 64; ++k) a3 = fmaf(h2s[b][k], W[10368 + k*32 + j], a3);
    state_out[b*32 + j] = softplus_f(a3);
  }
}

// ---------------- launcher ----------------
// ws (4-byte units): counts[32768]@0 | offsets[32768]@32768 | woff[32768]@65536 |
//   list[1048576]@98304 | bondsum[128]@1146880 | atomsum[128]@1147008 | W[39392]@1147136
extern "C" void kernel_launch(void* const* d_in, const int* in_sizes, int n_in,
                              void* d_out, int out_size, void* d_ws, size_t ws_size,
                              hipStream_t stream)
{
  (void)in_sizes; (void)n_in; (void)out_size; (void)ws_size;
  const float* bonds = (const float*)d_in[0];
  const int*   ba1   = (const int*)d_in[1];
  const int*   ba2   = (const int*)d_in[2];
  const float* atoms = (const float*)d_in[3];
  const float* state = (const float*)d_in[4];

  int*   counts  = (int*)d_ws;
  int*   offsets = counts + 32768;
  int*   woff    = counts + 65536;
  int*   list    = counts + 98304;
  float* bondsum = (float*)d_ws + 1146880;
  float* atomsum = (float*)d_ws + 1147008;
  float* W       = (float*)d_ws + 1147136;

  hipMemsetAsync(counts, 0, 32768 * sizeof(int), stream);
  hipMemsetAsync(bondsum, 0, 256 * sizeof(float), stream);

  WPtrs wp;
  for (int s = 0; s < 18; ++s) wp.p[s] = (const float*)d_in[5 + s];
  prep_kernel<<<154, 256, 0, stream>>>(wp, W);

  hist_kernel<<<(B_*NB_)/256, 256, 0, stream>>>(ba1, counts);
  scan_kernel<<<1, 1024, 0, stream>>>(counts, offsets, woff);
  fill_kernel<<<(B_*NB_)/256, 256, 0, stream>>>(ba1, woff, list);

  float* out_bonds = (float*)d_out;
  float* out_atoms = out_bonds + (size_t)B_*NB_*32;
  float* out_state = out_atoms + (size_t)B_*NA_*32;

  bonds_kernel<<<dim3(NB_/256, B_), 256, 0, stream>>>(bonds, ba1, ba2, atoms, state,
                                                      W, out_bonds);
  atoms_kernel<<<dim3(NA_/64, B_), 64, 0, stream>>>(atoms, state, W + 14496,
                                                    counts, offsets, list, out_bonds,
                                                    out_atoms, bondsum, atomsum);
  state_kernel<<<1, 256, 0, stream>>>(state, W + 26944, bondsum, atomsum, out_state);
}

// Round 5
// 663.306 us; speedup vs baseline: 3.4843x; 1.3629x over previous
//
#include <hip/hip_runtime.h>

#define B_   4
#define NB_  262144
#define NA_  8192
#define NB_SHIFT 18

typedef short bf16x8 __attribute__((ext_vector_type(8)));
typedef float f32x4  __attribute__((ext_vector_type(4)));

// ---------------- helpers ----------------
__device__ __forceinline__ float bflo(unsigned int u){ return __uint_as_float(u << 16); }
__device__ __forceinline__ float bfhi(unsigned int u){ return __uint_as_float(u & 0xffff0000u); }
__device__ __forceinline__ unsigned short f2bf(float f){
  unsigned int u = __float_as_uint(f);
  u += 0x7fffu + ((u >> 16) & 1u);   // round-to-nearest-even
  return (unsigned short)(u >> 16);
}
__device__ __forceinline__ unsigned int packbf(float a, float b){
  return (unsigned int)f2bf(a) | ((unsigned int)f2bf(b) << 16);
}
__device__ __forceinline__ float softplus_f(float v){
  return fmaxf(v, 0.0f) + __logf(1.0f + __expf(-fabsf(v)));
}
__device__ __forceinline__ void store32f(float* dst, const float* v){
  float4* p = reinterpret_cast<float4*>(dst);
  #pragma unroll
  for (int q = 0; q < 8; ++q)
    p[q] = make_float4(v[4*q+0], v[4*q+1], v[4*q+2], v[4*q+3]);
}

// stage 32 f32 from src into 16 packed-bf16-pair LDS rows r0..r0+15 (row stride = ncol)
__device__ __forceinline__ void stage32(unsigned int* xbuf, int tid, int r0,
                                        const float* __restrict__ src, int ncol){
  const float4* p = reinterpret_cast<const float4*>(src);
  #pragma unroll
  for (int q = 0; q < 8; ++q){
    float4 v = p[q];
    xbuf[(r0 + 2*q    )*ncol + tid] = packbf(v.x, v.y);
    xbuf[(r0 + 2*q + 1)*ncol + tid] = packbf(v.z, v.w);
  }
}

// layers 2 (64->64) + 3 (64->32) VALU path; h1 in 32 packed rows. Columns thread-private.
__device__ __forceinline__ void mlp_tail_packed(unsigned int* hbuf, int tid, int ncol,
                                         const float* __restrict__ W2, const float* __restrict__ B2,
                                         const float* __restrict__ W3, const float* __restrict__ B3,
                                         float* out)
{
  float acc[64];
  #pragma unroll
  for (int j = 0; j < 64; ++j) acc[j] = B2[j];
  for (int k2 = 0; k2 < 32; ++k2){
    unsigned int px = hbuf[k2*ncol + tid];
    float x0 = bflo(px), x1 = bfhi(px);
    const float* w = W2 + k2*128;
    #pragma unroll
    for (int j = 0; j < 64; ++j) acc[j] = fmaf(x0, w[j], acc[j]);
    #pragma unroll
    for (int j = 0; j < 64; ++j) acc[j] = fmaf(x1, w[64+j], acc[j]);
  }
  #pragma unroll
  for (int j2 = 0; j2 < 32; ++j2)
    hbuf[j2*ncol + tid] = packbf(softplus_f(acc[2*j2]), softplus_f(acc[2*j2+1]));

  float a3[32];
  #pragma unroll
  for (int j = 0; j < 32; ++j) a3[j] = B3[j];
  for (int k2 = 0; k2 < 32; ++k2){
    unsigned int px = hbuf[k2*ncol + tid];
    float x0 = bflo(px), x1 = bfhi(px);
    const float* w = W3 + k2*64;
    #pragma unroll
    for (int j = 0; j < 32; ++j) a3[j] = fmaf(x0, w[j], a3[j]);
    #pragma unroll
    for (int j = 0; j < 32; ++j) a3[j] = fmaf(x1, w[32+j], a3[j]);
  }
  #pragma unroll
  for (int j = 0; j < 32; ++j) out[j] = softplus_f(a3[j]);
}

// ---------------- weight prep: concat the 18 f32 arrays ----------------
struct WPtrs { const float* p[18]; };

__global__ __launch_bounds__(256) void prep_kernel(WPtrs wp, float* __restrict__ W){
  int i = blockIdx.x * 256 + threadIdx.x;
  if (i >= 39392) return;
  int idx = i;
  const int sizes[18] = {8192,64,4096,64,2048,32,
                         6144,64,4096,64,2048,32,
                         6144,64,4096,64,2048,32};
  #pragma unroll
  for (int s = 0; s < 18; ++s){
    if (idx < sizes[s]){ W[i] = wp.p[s][idx]; return; }
    idx -= sizes[s];
  }
}

// ---------------- swizzle e-MLP weights into MFMA B-fragment order (bf16) ----------------
// B-frag for 16x16x32: lane holds B[k = quad*8 + j][n = (lane&15)]
// W1b @0 (8192): frag (kt,nt) g=kt*4+nt, kt<4,nt<4 ; W2b @8192 (4096): g=kt*4+nt, kt<2
// W3b @12288 (2048): g=kt*2+nt, kt<2, nt<2
__global__ __launch_bounds__(256) void swizzle_kernel(
    const float* __restrict__ ew1, const float* __restrict__ ew2,
    const float* __restrict__ ew3, unsigned short* __restrict__ Wb){
  int i = blockIdx.x*256 + threadIdx.x;
  if (i >= 14336) return;
  int j = i & 7, lane = (i >> 3) & 63;
  int quad = lane >> 4, l16 = lane & 15;
  float v;
  if (i < 8192){
    int g = i >> 9;  int nt = g & 3, kt = g >> 2;
    v = ew1[(kt*32 + quad*8 + j)*64 + nt*16 + l16];
  } else if (i < 12288){
    int g = (i - 8192) >> 9;  int nt = g & 3, kt = g >> 2;
    v = ew2[(kt*32 + quad*8 + j)*64 + nt*16 + l16];
  } else {
    int g = (i - 12288) >> 9;  int nt = g & 1, kt = g >> 1;
    v = ew3[(kt*32 + quad*8 + j)*32 + nt*16 + l16];
  }
  Wb[i] = f2bf(v);
}

// ---------------- CSR build ----------------
__global__ __launch_bounds__(256) void hist_kernel(const int* __restrict__ ba1,
                                                   int* __restrict__ counts){
  int i = blockIdx.x * 256 + threadIdx.x;
  int b = i >> NB_SHIFT;
  atomicAdd(&counts[b*NA_ + ba1[i]], 1);
}

__global__ __launch_bounds__(1024) void scan_kernel(const int* __restrict__ counts,
                                                    int* __restrict__ offsets,
                                                    int* __restrict__ woff){
  __shared__ int s[1024];
  const int tid = threadIdx.x;
  const int base = tid * 32;
  int local[32]; int sum = 0;
  #pragma unroll
  for (int i = 0; i < 32; ++i){ local[i] = counts[base + i]; sum += local[i]; }
  s[tid] = sum;
  __syncthreads();
  for (int off = 1; off < 1024; off <<= 1){
    int v = (tid >= off) ? s[tid - off] : 0;
    __syncthreads();
    s[tid] += v;
    __syncthreads();
  }
  int run = s[tid] - sum;
  #pragma unroll
  for (int i = 0; i < 32; ++i){
    offsets[base + i] = run; woff[base + i] = run; run += local[i];
  }
}

__global__ __launch_bounds__(256) void fill_kernel(const int* __restrict__ ba1,
                                                   int* __restrict__ woff,
                                                   int* __restrict__ list){
  int i = blockIdx.x * 256 + threadIdx.x;
  int b = i >> NB_SHIFT;
  int pos = atomicAdd(&woff[b*NA_ + ba1[i]], 1);
  list[pos] = i & (NB_ - 1);
}

// ---------------- stage 1: bonds MLP via MFMA (128->64->64->32) ----------------
// Per wave: 64 bonds. A-frags gathered straight from global (kt: 0=a1,1=a2,2=bond,3=state).
// H round-trip per wave in LDS, stride 72 shorts (reads 2-way free, writes 4-way).
__global__ __launch_bounds__(256) void bonds_kernel(
    const float* __restrict__ bonds,
    const int* __restrict__ ba1,
    const int* __restrict__ ba2,
    const float* __restrict__ atoms,
    const float* __restrict__ state,
    const float* __restrict__ W,            // f32 concat (biases)
    const unsigned short* __restrict__ Wb,  // swizzled bf16 e-weights
    float* __restrict__ bonds_out)
{
  __shared__ unsigned short hred[4][64*72];
  const int tid  = threadIdx.x;
  const int wave = tid >> 6, lane = tid & 63;
  const int quad = lane >> 4, l16 = lane & 15;
  const int b = blockIdx.y;
  const int rowbase = blockIdx.x*256 + wave*64;   // bond row within batch
  unsigned short* H = &hred[wave][0];

  int r[4], g1[4], g2[4];
  #pragma unroll
  for (int t = 0; t < 4; ++t){
    r[t]  = rowbase + t*16 + l16;
    g1[t] = ba1[(size_t)b*NB_ + r[t]];
    g2[t] = ba2[(size_t)b*NB_ + r[t]];
  }

  // ----- layer 1: [64x128] @ [128x64] -----
  f32x4 acc[4][4] = {};
  #pragma unroll
  for (int kt = 0; kt < 4; ++kt){
    bf16x8 bf[4];
    #pragma unroll
    for (int nt = 0; nt < 4; ++nt)
      bf[nt] = *(const bf16x8*)(Wb + ((kt*4 + nt)*64 + lane)*8);
    #pragma unroll
    for (int t = 0; t < 4; ++t){
      const float* src;
      if      (kt == 0) src = atoms + ((size_t)b*NA_ + g1[t])*32 + quad*8;
      else if (kt == 1) src = atoms + ((size_t)b*NA_ + g2[t])*32 + quad*8;
      else if (kt == 2) src = bonds + ((size_t)b*NB_ + r[t])*32 + quad*8;
      else              src = state + (size_t)b*32 + quad*8;
      float4 v0 = *(const float4*)(src);
      float4 v1 = *(const float4*)(src + 4);
      bf16x8 af;
      af[0]=(short)f2bf(v0.x); af[1]=(short)f2bf(v0.y); af[2]=(short)f2bf(v0.z); af[3]=(short)f2bf(v0.w);
      af[4]=(short)f2bf(v1.x); af[5]=(short)f2bf(v1.y); af[6]=(short)f2bf(v1.z); af[7]=(short)f2bf(v1.w);
      #pragma unroll
      for (int nt = 0; nt < 4; ++nt)
        acc[t][nt] = __builtin_amdgcn_mfma_f32_16x16x32_bf16(af, bf[nt], acc[t][nt], 0, 0, 0);
    }
  }
  // bias + softplus -> H1 (bf16, [64 m][64 n], stride 72)
  {
    const float* b1v = W + 8192;
    #pragma unroll
    for (int nt = 0; nt < 4; ++nt){
      float bias = b1v[nt*16 + l16];
      #pragma unroll
      for (int t = 0; t < 4; ++t){
        #pragma unroll
        for (int rg = 0; rg < 4; ++rg){
          int m = t*16 + quad*4 + rg;
          H[m*72 + nt*16 + l16] = f2bf(softplus_f(acc[t][nt][rg] + bias));
        }
      }
    }
  }

  // ----- layer 2: [64x64] @ [64x64] -----
  f32x4 acc2[4][4] = {};
  #pragma unroll
  for (int kt = 0; kt < 2; ++kt){
    bf16x8 bf[4];
    #pragma unroll
    for (int nt = 0; nt < 4; ++nt)
      bf[nt] = *(const bf16x8*)(Wb + 8192 + ((kt*4 + nt)*64 + lane)*8);
    #pragma unroll
    for (int t = 0; t < 4; ++t){
      bf16x8 af = *(const bf16x8*)(H + (t*16 + l16)*72 + kt*32 + quad*8);
      #pragma unroll
      for (int nt = 0; nt < 4; ++nt)
        acc2[t][nt] = __builtin_amdgcn_mfma_f32_16x16x32_bf16(af, bf[nt], acc2[t][nt], 0, 0, 0);
    }
  }
  {
    const float* b2v = W + 12352;
    #pragma unroll
    for (int nt = 0; nt < 4; ++nt){
      float bias = b2v[nt*16 + l16];
      #pragma unroll
      for (int t = 0; t < 4; ++t){
        #pragma unroll
        for (int rg = 0; rg < 4; ++rg){
          int m = t*16 + quad*4 + rg;
          H[m*72 + nt*16 + l16] = f2bf(softplus_f(acc2[t][nt][rg] + bias));
        }
      }
    }
  }

  // ----- layer 3: [64x64] @ [64x32] -----
  f32x4 acc3[4][2] = {};
  #pragma unroll
  for (int kt = 0; kt < 2; ++kt){
    bf16x8 bf[2];
    #pragma unroll
    for (int nt = 0; nt < 2; ++nt)
      bf[nt] = *(const bf16x8*)(Wb + 12288 + ((kt*2 + nt)*64 + lane)*8);
    #pragma unroll
    for (int t = 0; t < 4; ++t){
      bf16x8 af = *(const bf16x8*)(H + (t*16 + l16)*72 + kt*32 + quad*8);
      #pragma unroll
      for (int nt = 0; nt < 2; ++nt)
        acc3[t][nt] = __builtin_amdgcn_mfma_f32_16x16x32_bf16(af, bf[nt], acc3[t][nt], 0, 0, 0);
    }
  }
  {
    const float* b3v = W + 14464;
    #pragma unroll
    for (int nt = 0; nt < 2; ++nt){
      float bias = b3v[nt*16 + l16];
      #pragma unroll
      for (int t = 0; t < 4; ++t){
        #pragma unroll
        for (int rg = 0; rg < 4; ++rg){
          int m = t*16 + quad*4 + rg;
          bonds_out[((size_t)b*NB_ + rowbase + m)*32 + nt*16 + l16] =
              softplus_f(acc3[t][nt][rg] + bias);
        }
      }
    }
  }
}

// ---------------- gather: sum bonds_out rows per atom -> packed bf16 bta ----------------
// 8 threads per atom, thread handles a 4-col chunk.
__global__ __launch_bounds__(256) void gather_kernel(
    const int* __restrict__ counts,
    const int* __restrict__ offsets,
    const int* __restrict__ list,
    const float* __restrict__ bonds_out,
    unsigned int* __restrict__ btap)
{
  int i = blockIdx.x*256 + threadIdx.x;   // [0, B*NA*8)
  int p = i & 7;
  int row = i >> 3;                        // b*NA + atom
  int b = row >> 13;                       // NA = 2^13
  int c = counts[row], o = offsets[row];
  const float* basep = bonds_out + (size_t)b*NB_*32 + p*4;
  float4 acc = make_float4(0.f, 0.f, 0.f, 0.f);
  int t = 0;
  for (; t + 2 <= c; t += 2){
    int i0 = list[o+t], i1 = list[o+t+1];
    float4 v0 = *(const float4*)(basep + (size_t)i0*32);
    float4 v1 = *(const float4*)(basep + (size_t)i1*32);
    acc.x += v0.x + v1.x; acc.y += v0.y + v1.y;
    acc.z += v0.z + v1.z; acc.w += v0.w + v1.w;
  }
  if (t < c){
    int i0 = list[o+t];
    float4 v0 = *(const float4*)(basep + (size_t)i0*32);
    acc.x += v0.x; acc.y += v0.y; acc.z += v0.z; acc.w += v0.w;
  }
  btap[(size_t)row*16 + p*2    ] = packbf(acc.x, acc.y);
  btap[(size_t)row*16 + p*2 + 1] = packbf(acc.z, acc.w);
}

// ---------------- stage 2: atoms MLP (96->64->64->32) ----------------
// W(v): w1[96][64] @0 | b1 @6144 | w2 @6208 | b2 @10304 | w3 @10368 | b3 @12416
__global__ __launch_bounds__(64) void atoms_kernel(
    const float* __restrict__ atoms,
    const float* __restrict__ state,
    const float* __restrict__ W,
    const int* __restrict__ counts,
    const unsigned int* __restrict__ btap,
    float* __restrict__ atoms_out,
    float* __restrict__ bondsum,
    float* __restrict__ atomsum)
{
  __shared__ unsigned int xbuf[48*64];
  const int tid = threadIdx.x;            // one wave
  const int b = blockIdx.y;
  const int row = b*NA_ + blockIdx.x*64 + tid;

  float braw[32];
  {
    const uint4* pb = reinterpret_cast<const uint4*>(btap + (size_t)row*16);
    #pragma unroll
    for (int q = 0; q < 4; ++q){
      uint4 v = pb[q];
      braw[8*q+0]=bflo(v.x); braw[8*q+1]=bfhi(v.x);
      braw[8*q+2]=bflo(v.y); braw[8*q+3]=bfhi(v.y);
      braw[8*q+4]=bflo(v.z); braw[8*q+5]=bfhi(v.z);
      braw[8*q+6]=bflo(v.w); braw[8*q+7]=bfhi(v.w);
    }
  }
  const float inv = 1.0f / (float)counts[row];
  #pragma unroll
  for (int q = 0; q < 16; ++q)
    xbuf[q*64 + tid] = packbf(braw[2*q]*inv, braw[2*q+1]*inv);     // v_in 0..31
  stage32(xbuf, tid, 16, atoms + (size_t)row*32, 64);              // v_in 32..63
  stage32(xbuf, tid, 32, state + (size_t)b*32,   64);              // v_in 64..95

  float acc[64];
  {
    const float* Bl = W + 6144;
    #pragma unroll
    for (int j = 0; j < 64; ++j) acc[j] = Bl[j];
  }
  for (int k2 = 0; k2 < 48; ++k2){
    unsigned int px = xbuf[k2*64 + tid];
    float x0 = bflo(px), x1 = bfhi(px);
    const float* w = W + k2*128;
    #pragma unroll
    for (int j = 0; j < 64; ++j) acc[j] = fmaf(x0, w[j], acc[j]);
    #pragma unroll
    for (int j = 0; j < 64; ++j) acc[j] = fmaf(x1, w[64+j], acc[j]);
  }
  #pragma unroll
  for (int j2 = 0; j2 < 32; ++j2)
    xbuf[j2*64 + tid] = packbf(softplus_f(acc[2*j2]), softplus_f(acc[2*j2+1]));

  float out[32];
  mlp_tail_packed(xbuf, tid, 64, W + 6208, W + 10304, W + 10368, W + 12416, out);
  store32f(atoms_out + (size_t)row*32, out);

  #pragma unroll
  for (int f = 0; f < 32; ++f){
    float v = braw[f];
    #pragma unroll
    for (int s = 1; s < 64; s <<= 1) v += __shfl_xor(v, s);
    if (tid == 0) unsafeAtomicAdd(&bondsum[b*32 + f], v);
  }
  #pragma unroll
  for (int f = 0; f < 32; ++f){
    float v = out[f];
    #pragma unroll
    for (int s = 1; s < 64; s <<= 1) v += __shfl_xor(v, s);
    if (tid == 0) unsafeAtomicAdd(&atomsum[b*32 + f], v);
  }
}

// ---------------- stage 3: state MLP (96->64->64->32), 4 rows ----------------
__global__ __launch_bounds__(256) void state_kernel(
    const float* __restrict__ state,
    const float* __restrict__ W,
    const float* __restrict__ bondsum,
    const float* __restrict__ atomsum,
    float* __restrict__ state_out)
{
  __shared__ float uin[4][96];
  __shared__ float h1s[4][64];
  __shared__ float h2s[4][64];
  const int tid = threadIdx.x;
  const int b = tid >> 6;
  const int j = tid & 63;
  if (j < 32){
    uin[b][j]      = bondsum[b*32 + j] * (1.0f/(float)NB_);
    uin[b][32 + j] = atomsum[b*32 + j] * (1.0f/(float)NA_);
    uin[b][64 + j] = state[(size_t)b*32 + j];
  }
  __syncthreads();
  float a1 = W[6144 + j];
  for (int k = 0; k < 96; ++k) a1 = fmaf(uin[b][k], W[k*64 + j], a1);
  h1s[b][j] = softplus_f(a1);
  __syncthreads();
  float a2 = W[10304 + j];
  for (int k = 0; k < 64; ++k) a2 = fmaf(h1s[b][k], W[6208 + k*64 + j], a2);
  h2s[b][j] = softplus_f(a2);
  __syncthreads();
  if (j < 32){
    float a3 = W[12416 + j];
    for (int k = 0; k < 64; ++k) a3 = fmaf(h2s[b][k], W[10368 + k*32 + j], a3);
    state_out[b*32 + j] = softplus_f(a3);
  }
}

// ---------------- launcher ----------------
// ws (4-byte units): counts[32768]@0 | offsets@32768 | woff@65536 | list[1048576]@98304 |
//   btap[524288]@1146880 | bondsum[128]@1671168 | atomsum[128]@1671296 |
//   W f32[39392]@1671424 | Wb u16[14336]@1710816 (7168 dwords) — total ~6.87 MB
extern "C" void kernel_launch(void* const* d_in, const int* in_sizes, int n_in,
                              void* d_out, int out_size, void* d_ws, size_t ws_size,
                              hipStream_t stream)
{
  (void)in_sizes; (void)n_in; (void)out_size; (void)ws_size;
  const float* bonds = (const float*)d_in[0];
  const int*   ba1   = (const int*)d_in[1];
  const int*   ba2   = (const int*)d_in[2];
  const float* atoms = (const float*)d_in[3];
  const float* state = (const float*)d_in[4];

  int*          counts  = (int*)d_ws;
  int*          offsets = counts + 32768;
  int*          woff    = counts + 65536;
  int*          list    = counts + 98304;
  unsigned int* btap    = (unsigned int*)d_ws + 1146880;
  float*        bondsum = (float*)d_ws + 1671168;
  float*        atomsum = (float*)d_ws + 1671296;
  float*        W       = (float*)d_ws + 1671424;
  unsigned short* Wb    = (unsigned short*)((unsigned int*)d_ws + 1710816);

  hipMemsetAsync(counts, 0, 32768 * sizeof(int), stream);
  hipMemsetAsync(bondsum, 0, 256 * sizeof(float), stream);

  WPtrs wp;
  for (int s = 0; s < 18; ++s) wp.p[s] = (const float*)d_in[5 + s];
  prep_kernel<<<154, 256, 0, stream>>>(wp, W);
  swizzle_kernel<<<56, 256, 0, stream>>>((const float*)d_in[5], (const float*)d_in[7],
                                         (const float*)d_in[9], Wb);

  hist_kernel<<<(B_*NB_)/256, 256, 0, stream>>>(ba1, counts);
  scan_kernel<<<1, 1024, 0, stream>>>(counts, offsets, woff);
  fill_kernel<<<(B_*NB_)/256, 256, 0, stream>>>(ba1, woff, list);

  float* out_bonds = (float*)d_out;
  float* out_atoms = out_bonds + (size_t)B_*NB_*32;
  float* out_state = out_atoms + (size_t)B_*NA_*32;

  bonds_kernel<<<dim3(NB_/256, B_), 256, 0, stream>>>(bonds, ba1, ba2, atoms, state,
                                                      W, Wb, out_bonds);
  gather_kernel<<<(B_*NA_*8)/256, 256, 0, stream>>>(counts, offsets, list, out_bonds, btap);
  atoms_kernel<<<dim3(NA_/64, B_), 64, 0, stream>>>(atoms, state, W + 14496,
                                                    counts, btap, out_atoms, bondsum, atomsum);
  state_kernel<<<1, 256, 0, stream>>>(state, W + 26944, bondsum, atomsum, out_state);
}